// Round 5
// baseline (288.911 us; speedup 1.0000x reference)
//
#include <hip/hip_runtime.h>
#include <hip/hip_bf16.h>
#include <math.h>

// Problem constants (static config in reference)
#define NT      4096              // B*T
#define DD      1024              // D
#define EE      8                 // experts
#define KK      2                 // top-k
#define CAP     1280              // EXP_CAP
#define CBN     (NT * EE * CAP)   // 41,943,040 elements per big output
#define NROW    (NT * EE)         // 32768 (t,e) rows per section
#define F4ROW   (CAP / 4)         // 320 float4 per row

#define NB      256               // persistent blocks (1/CU guaranteed co-resident)
#define NWAVES  (NB * 4)          // 1024 waves
#define RPW     (2 * NROW / NWAVES) // 64 virtual rows per wave

// LDS index swizzle (involution): spreads per-thread contiguous-32 walks
// across all banks.
__device__ __forceinline__ int swz(int j) { return j ^ ((j >> 5) & 31); }

// Device-scope grid barrier: monotonic counter within one replay (counter is
// zeroed by a memset node at graph start). ACQ_REL add releases this block's
// prior writes; ACQUIRE spin-load makes all arrived blocks' writes visible.
__device__ __forceinline__ void gridbar(unsigned* cnt, unsigned target) {
    __syncthreads();
    if (threadIdx.x == 0) {
        __hip_atomic_fetch_add(cnt, 1u, __ATOMIC_ACQ_REL, __HIP_MEMORY_SCOPE_AGENT);
        while (__hip_atomic_load(cnt, __ATOMIC_ACQUIRE, __HIP_MEMORY_SCOPE_AGENT) < target)
            __builtin_amdgcn_s_sleep(2);
    }
    __syncthreads();
}

// ---------------------------------------------------------------------------
// One persistent kernel: phase1 logits -> bar -> phase2 rank tables (block 0)
// -> bar -> phase3 streaming writer. 256 blocks x 256 threads, 64KB LDS.
// ---------------------------------------------------------------------------
__global__ __launch_bounds__(256) void fused_router_kernel(
    const float* __restrict__ x,        // (NT, D)
    const float* __restrict__ w,        // (E, D)
    float* __restrict__ out,
    unsigned* __restrict__ cnt,
    int* __restrict__ e0, int* __restrict__ e1,
    float* __restrict__ p0, float* __restrict__ p1,
    int* __restrict__ sl, float* __restrict__ val)
{
    __shared__ union {
        float wl[EE * DD];                              // 32 KB (phase 1)
        struct { int se[KK * NT]; float sp[KK * NT]; } s2;  // 64 KB (phase 2)
    } u;
    __shared__ unsigned long long wsumA[4], wsumB[4];

    const int tid  = threadIdx.x;
    const int wave = tid >> 6;
    const int lane = tid & 63;

    // ---------------- Phase 1: logits + top-2 + softmax ----------------
    for (int i = tid; i < EE * DD / 4; i += 256)
        reinterpret_cast<float4*>(u.wl)[i] = reinterpret_cast<const float4*>(w)[i];
    __syncthreads();

    const int wid = blockIdx.x * 4 + wave;              // 0..1023
    for (int t = wid; t < NT; t += NWAVES) {
        const float4* xt = reinterpret_cast<const float4*>(x + (size_t)t * DD);
        float acc[EE];
        #pragma unroll
        for (int e = 0; e < EE; ++e) acc[e] = 0.0f;

        #pragma unroll
        for (int ii = 0; ii < DD / 4 / 64; ++ii) {      // 4 iters
            const int i = ii * 64 + lane;
            const float4 xv = xt[i];
            #pragma unroll
            for (int e = 0; e < EE; ++e) {
                const float4 wv = reinterpret_cast<const float4*>(u.wl + e * DD)[i];
                acc[e] += xv.x * wv.x + xv.y * wv.y + xv.z * wv.z + xv.w * wv.w;
            }
        }

        #pragma unroll
        for (int e = 0; e < EE; ++e) {
            float v = acc[e];
            #pragma unroll
            for (int off = 32; off > 0; off >>= 1) v += __shfl_xor(v, off);
            acc[e] = v;
        }

        if (lane == 0) {
            int b0 = 0; float l0 = acc[0];
            #pragma unroll
            for (int e = 1; e < EE; ++e) { if (acc[e] > l0) { l0 = acc[e]; b0 = e; } }
            int b1 = -1; float l1 = -INFINITY;
            #pragma unroll
            for (int e = 0; e < EE; ++e) { if (e != b0 && acc[e] > l1) { l1 = acc[e]; b1 = e; } }

            const float z  = expf(l1 - l0);             // l1 <= l0
            const float pa = 1.0f / (1.0f + z);
            const float pb = z * pa;

            e0[t] = b0; e1[t] = b1;
            p0[t] = pa; p1[t] = pb;
        }
    }

    gridbar(cnt, NB);                                   // all logits visible

    // ---------------- Phase 2: ordered rank -> tables (block 0) ----------------
    if (blockIdx.x == 0) {
        // init slot table to -1
        int4* sl4 = reinterpret_cast<int4*>(sl);
        const int4 neg = make_int4(-1, -1, -1, -1);
        for (int i = tid; i < NROW / 4; i += 256) sl4[i] = neg;

        // coalesced stage of assignments into LDS
        for (int i = tid; i < NT; i += 256) {
            u.s2.se[swz(i)]      = e0[i];
            u.s2.se[swz(NT + i)] = e1[i];
            u.s2.sp[swz(i)]      = p0[i];
            u.s2.sp[swz(NT + i)] = p1[i];
        }
        __syncthreads();

        const int base = tid * 32;
        unsigned long long ca = 0ull, cb = 0ull;        // experts 0-3 / 4-7, 16b fields
        #pragma unroll
        for (int i = 0; i < 32; ++i) {
            const int e = u.s2.se[swz(base + i)];
            if (e < 4) ca += 1ull << (16 * e);
            else       cb += 1ull << (16 * (e - 4));
        }

        unsigned long long sa = ca, sb = cb;            // intra-wave inclusive scan
        #pragma unroll
        for (int off = 1; off < 64; off <<= 1) {
            const unsigned long long ta = __shfl_up(sa, off);
            const unsigned long long tb = __shfl_up(sb, off);
            if ((tid & 63) >= off) { sa += ta; sb += tb; }
        }
        if ((tid & 63) == 63) { wsumA[wave] = sa; wsumB[wave] = sb; }
        __syncthreads();

        unsigned long long preA = 0ull, preB = 0ull;
        #pragma unroll
        for (int k = 0; k < 4; ++k) {
            if (k < wave) { preA += wsumA[k]; preB += wsumB[k]; }
        }
        unsigned long long ra = preA + sa - ca;         // exclusive prefix
        unsigned long long rb = preB + sb - cb;

        // replay in ascending j order; fill tables
        #pragma unroll
        for (int i = 0; i < 32; ++i) {
            const int j = base + i;
            const int e = u.s2.se[swz(j)];
            int rank;
            if (e < 4) { rank = (int)((ra >> (16 * e)) & 0xFFFF);       ra += 1ull << (16 * e); }
            else       { rank = (int)((rb >> (16 * (e - 4))) & 0xFFFF); rb += 1ull << (16 * (e - 4)); }
            if (rank < CAP) {
                const int t = j & (NT - 1);
                sl[t * EE + e]  = rank;
                val[t * EE + e] = u.s2.sp[swz(j)];
            }
        }

        // used_cap -> out[0..7]
        if (tid < EE) {
            const unsigned long long totA = wsumA[0] + wsumA[1] + wsumA[2] + wsumA[3];
            const unsigned long long totB = wsumB[0] + wsumB[1] + wsumB[2] + wsumB[3];
            const int e = tid;
            const int tot = (e < 4) ? (int)((totA >> (16 * e)) & 0xFFFF)
                                    : (int)((totB >> (16 * (e - 4))) & 0xFFFF);
            out[e] = (float)((tot < CAP) ? tot : CAP);
        }
    }

    gridbar(cnt, 2 * NB);                               // tables visible

    // ---------------- Phase 3: fill-isomorphic streaming writer ----------------
    // 65536 virtual rows cover [weights | mask] contiguously (stride 1280 f32).
    const int gw = blockIdx.x * 4 + wave;               // 0..1023
    float4* base4 = reinterpret_cast<float4*>(out + 8);

    for (int rr = 0; rr < RPW; ++rr) {
        const int vr = gw * RPW + rr;                   // virtual row
        const int r  = __builtin_amdgcn_readfirstlane(vr & (NROW - 1));
        const int   s = sl[r];                          // wave-uniform s_load
        const float p = val[r];
        const bool  on = (s >= 0) && (p != 0.0f);
        const float hv = (vr >= NROW) ? 1.0f : p;       // mask section -> 1.0

        float4* dst = base4 + (size_t)vr * F4ROW;
        #pragma unroll
        for (int it = 0; it < 5; ++it) {
            const int f4 = (it << 6) + lane;            // 0..319
            const int c  = f4 << 2;
            float4 v;
            v.x = (on && s == c)     ? hv : 0.0f;
            v.y = (on && s == c + 1) ? hv : 0.0f;
            v.z = (on && s == c + 2) ? hv : 0.0f;
            v.w = (on && s == c + 3) ? hv : 0.0f;
            dst[f4] = v;
        }
    }
}

// ---------------------------------------------------------------------------
extern "C" void kernel_launch(void* const* d_in, const int* in_sizes, int n_in,
                              void* d_out, int out_size, void* d_ws, size_t ws_size,
                              hipStream_t stream) {
    const float* x = (const float*)d_in[0];     // (B,T,D) f32
    const float* w = (const float*)d_in[1];     // (E,D)   f32
    float* out = (float*)d_out;

    char* ws = (char*)d_ws;
    unsigned* cnt = (unsigned*)(ws);                    // 64 B barrier counter
    int*   e0  = (int*)(ws + 1 * 1024);                 // 16 KB
    int*   e1  = (int*)(ws + 17 * 1024);                // 16 KB
    float* p0  = (float*)(ws + 33 * 1024);              // 16 KB
    float* p1  = (float*)(ws + 49 * 1024);              // 16 KB
    int*   sl  = (int*)(ws + 72 * 1024);                // 128 KB (NROW ints)
    float* val = (float*)(ws + 200 * 1024);             // 128 KB (NROW floats)

    // zero the barrier counter each replay (tiny memset node, poison-proof)
    hipMemsetAsync(cnt, 0, 64, stream);

    // single persistent kernel: logits -> bar -> rank tables -> bar -> write
    fused_router_kernel<<<NB, 256, 0, stream>>>(x, w, out, cnt, e0, e1, p0, p1, sl, val);
}